// Round 1
// baseline (975.717 us; speedup 1.0000x reference)
//
#include <hip/hip_runtime.h>

// OLSTM: T=20 frames, N=50000 nodes, K=10000 active peds/frame
// RNN=128, EMB=64, IN=2, OUT=5, G2=16
//
// Round 8: occupancy doubling. NODEB 98 -> 49 cuts LDS to ~73 KB so TWO blocks
// co-reside per CU (16 waves/CU vs 8): independent blocks hide each other's
// barrier/latency stalls. Per-frame critical path shortened: single-wave winner
// resolution (ballot compaction, 3 barriers -> 1), per-entry grid/x staging
// issued at frame start (latency overlapped with resolution), fused
// h-fill+embedding phase, second GEMM m-tile skipped when ms<=16 (common case,
// E[winners]=9.8), out-proj on transposed W_out with float4 loads, no
// post-out-proj barrier.
#define TT    20
#define NN    50000
#define KK    10000
#define RNN   128
#define EMB   64
#define GG2   16
#define NOUT  5
#define NODEB 49
#define NBLK  ((NN + NODEB - 1) / NODEB)   // 1021 blocks (block 1020 owns 20 nodes)
#define CAP   48                           // peds per (frame, block); E[n]=9.8, P(>48)~1e-15
#define NTHR  512                          // 8 waves

typedef __attribute__((ext_vector_type(8))) short bf16x8;
typedef __attribute__((ext_vector_type(4))) float f32x4;

__device__ __forceinline__ unsigned short f2b(float x) {  // fp32 -> bf16, RNE
    union { float f; unsigned u; } v; v.f = x;
    return (unsigned short)((v.u + 0x7FFF + ((v.u >> 16) & 1)) >> 16);
}
__device__ __forceinline__ unsigned pack2(float a, float b) {
    return (unsigned)f2b(a) | ((unsigned)f2b(b) << 16);
}
__device__ __forceinline__ float sigf(float x)   { return 1.f / (1.f + __expf(-x)); }
__device__ __forceinline__ float tanh_f(float x) { return 2.f / (1.f + __expf(-2.f * x)) - 1.f; }

struct Params {
    const float* input_data; const float* grids;
    const float* h0; const float* c0;
    const float* W_in;  const float* b_in;
    const float* W_obs; const float* b_obs;
    const float* b_out;
    float* outputs; float* h_all; float* c_all;
    const unsigned short* Wt; const float* biasp; const float* W_outT;
    const int* cnt; const int* lists;
};

struct SmemT {
    float hS[NODEB][132];          // owned h state, fp32 (pad 132: bank spread)
    float cS[NODEB][132];          // owned c state, fp32
    unsigned short uS[32][264];    // GEMM A: [ie(64) te(64) h(128)] bf16, 32-ped super-tile
    float gX[CAP][20];             // per-ENTRY staged grid row (16) + x (2)
    int eL[2][CAP];                // double-buffered entry lists
    int wL[CAP];                   // winner entries: k | nl<<14 | entry_slot<<21
    int wslot[NODEB];              // winner tags per node-local
    int s_cnt[2];
    int s_wn;
};                                 // 73,264 B -> 2 blocks/CU (146.5 KB of 160 KB)

// bf16 transposed+permuted weights Wt[cp][k] (512x256) + fused bias:
// cp = 64*wq + 16*gate + cl  ->  orig col = 128*gate + 16*wq + cl.
// Consumer wave w takes cp in [64w, 64w+64): its 4 n-tiles = gates i,f,g,o for
// rnn unit r = 16w + cl  =>  lane-local LSTM. Also builds W_outT[o][r].
__global__ __launch_bounds__(256) void prep_kernel(
    const float* __restrict__ Wih, const float* __restrict__ Whh,
    const float* __restrict__ bih, const float* __restrict__ bhh,
    const float* __restrict__ Wout,
    unsigned short* __restrict__ Wt, float* __restrict__ biasp,
    float* __restrict__ WoutT)
{
    int cp = blockIdx.x;       // 0..511
    int k  = threadIdx.x;      // 0..255
    int wq = cp >> 6, rem = cp & 63, gate = rem >> 4, cl = rem & 15;
    int oc = 128 * gate + 16 * wq + cl;
    float v = (k < 128) ? Wih[k * 512 + oc] : Whh[(k - 128) * 512 + oc];
    Wt[cp * 256 + k] = f2b(v);
    if (k == 0) biasp[cp] = bih[oc] + bhh[oc];
    int e = cp * 256 + k;
    if (e < NOUT * RNN) WoutT[e] = Wout[(e & 127) * NOUT + (e >> 7)];
}

// Bin each (t,k) ped to its node-owner block. Entry = k | (node_local << 14).
__global__ __launch_bounds__(256) void bin_kernel(
    const int* __restrict__ idx, int* __restrict__ cnt, int* __restrict__ lists)
{
    int e = blockIdx.x * 256 + threadIdx.x;
    if (e >= TT * KK) return;
    int t = e / KK, k = e - t * KK;
    int nd = idx[e];
    int ow = nd / NODEB, nl = nd - ow * NODEB;
    int slot = atomicAdd(&cnt[t * NBLK + ow], 1);
    if (slot < CAP) lists[((size_t)(t * NBLK + ow)) * CAP + slot] = k | (nl << 14);
}

__global__ __launch_bounds__(NTHR, 4) void olstm_kernel(Params P) {
    extern __shared__ char smem_raw[];
    SmemT& S = *(SmemT*)smem_raw;
    const int tid = threadIdx.x;
    const int b   = blockIdx.x;
    const int n0  = b * NODEB;
    const int nown = (NN - n0 < NODEB) ? (NN - n0) : NODEB;

    // ---- prologue: owned state -> LDS (coalesced), frame-0 entries ----
    for (int i = tid; i < nown * RNN; i += NTHR) {
        int nl = i >> 7, r = i & 127;
        S.hS[nl][r] = P.h0[(size_t)n0 * RNN + i];
        S.cS[nl][r] = P.c0[(size_t)n0 * RNN + i];
    }
    if (tid == 0) { int c = P.cnt[b]; S.s_cnt[0] = (c > CAP) ? CAP : c; }
    if (tid < CAP) S.eL[0][tid] = P.lists[(size_t)b * CAP + tid];
    __syncthreads();

    const int w = tid >> 6, lane = tid & 63;
    const int cl = lane & 15, kq = lane >> 4;

    for (int t = 0; t < TT; ++t) {
        const int buf = t & 1;
        const int cn = S.s_cnt[buf];
        // prefetch t+1 entry list into regs (committed at frame end)
        int pf_e = 0, pf_c = 0;
        if (t + 1 < TT) {
            if (tid < CAP) pf_e = P.lists[((size_t)((t + 1) * NBLK + b)) * CAP + tid];
            if (tid == 0)  pf_c = P.cnt[(t + 1) * NBLK + b];
        }
        // ---- issue x/grid loads for ALL entries (latency overlaps resolution) ----
        float2 xv = {0.f, 0.f};
        float4 gv = {0.f, 0.f, 0.f, 0.f};
        int gm = 0;
        if (tid < CAP) {
            if (tid < cn) {
                const int e2 = S.eL[buf][tid];
                const int nn2 = n0 + (e2 >> 14);
                xv = *(const float2*)(P.input_data + ((size_t)t * NN + nn2) * 2);
            }
        } else if (tid >= 64 && tid < 64 + 4 * CAP) {
            gm = (tid - 64) >> 2;
            if (gm < cn) {
                const int kk2 = S.eL[buf][gm] & 0x3FFF;
                gv = *(const float4*)(P.grids + ((size_t)t * KK + kk2) * GG2 + (tid & 3) * 4);
            }
        }
        // ---- wave-0 winner resolution (single wave: in-order DS, no block barriers) ----
        if (w == 0) {
            if (lane < nown) S.wslot[lane] = -1;
            int ent = 0, mk = -1, mnl = 0;
            const bool act = lane < cn;
            if (act) {
                ent = S.eL[buf][lane]; mnl = ent >> 14; mk = ent & 0x3FFF;
                atomicMax(&S.wslot[mnl], mk);
            }
            const bool win = act && (S.wslot[mnl] == mk);
            const unsigned long long ball = __ballot(win);
            const int slot = __popcll(ball & ((1ull << lane) - 1ull));
            if (win) S.wL[slot] = ent | (lane << 21);
            if (lane == 0) S.s_wn = __popcll(ball);
        }
        // ---- commit staged gX (vmcnt stall lands here, overlapped with wave 0) ----
        if (tid < CAP) {
            if (tid < cn) { S.gX[tid][16] = xv.x; S.gX[tid][17] = xv.y; }
        } else if (tid >= 64 && tid < 64 + 4 * CAP) {
            if (gm < cn) *(float4*)&S.gX[gm][(tid & 3) * 4] = gv;
        }
        __syncthreads();
        const int wn = S.s_wn;

        for (int base = 0; base < wn; base += 32) {
            const int ms = (wn - base < 32) ? (wn - base) : 32;
            const int nmt = (ms > 16) ? 2 : 1;         // skip m-tile 1 when ms<=16
            const int mrows = nmt << 4;
            // ---- fused uS build: h-part (float4 LDS reads -> bf16) + embeddings ----
            {
                const int m = tid >> 4, l = tid & 15;
                if (m < mrows) {
                    unsigned* du = (unsigned*)&S.uS[m][128 + l * 8];
                    unsigned* di = (unsigned*)&S.uS[m][l * 4];
                    unsigned* dt = (unsigned*)&S.uS[m][64 + l * 4];
                    if (m < ms) {
                        const int e = S.wL[base + m];
                        const int nl2 = (e >> 14) & 63;
                        const int slot = e >> 21;
                        const float4 h0 = *(const float4*)&S.hS[nl2][l * 8];
                        const float4 h1 = *(const float4*)&S.hS[nl2][l * 8 + 4];
                        du[0] = pack2(h0.x, h0.y); du[1] = pack2(h0.z, h0.w);
                        du[2] = pack2(h1.x, h1.y); du[3] = pack2(h1.z, h1.w);
                        const float x0 = S.gX[slot][16], x1 = S.gX[slot][17];
                        const int e0 = l * 4;
                        float iv[4], tv[4];
                        #pragma unroll
                        for (int j = 0; j < 4; ++j) {
                            iv[j] = fmaxf(fmaf(x0, P.W_in[e0 + j],
                                          fmaf(x1, P.W_in[64 + e0 + j], P.b_in[e0 + j])), 0.f);
                            tv[j] = P.b_obs[e0 + j];
                        }
                        #pragma unroll
                        for (int g = 0; g < GG2; ++g) {
                            const float gg = S.gX[slot][g];
                            #pragma unroll
                            for (int j = 0; j < 4; ++j)
                                tv[j] = fmaf(gg, P.W_obs[g * EMB + e0 + j], tv[j]);
                        }
                        di[0] = pack2(iv[0], iv[1]); di[1] = pack2(iv[2], iv[3]);
                        dt[0] = pack2(fmaxf(tv[0], 0.f), fmaxf(tv[1], 0.f));
                        dt[1] = pack2(fmaxf(tv[2], 0.f), fmaxf(tv[3], 0.f));
                    } else {
                        du[0] = 0; du[1] = 0; du[2] = 0; du[3] = 0;
                        di[0] = 0; di[1] = 0; dt[0] = 0; dt[1] = 0;
                    }
                }
            }
            __syncthreads();

            // ---- gates GEMM: wave w covers permuted cols [64w, 64w+64) ----
            f32x4 acc0[4], acc1[4];
            #pragma unroll
            for (int gate = 0; gate < 4; ++gate) {
                const float bv = P.biasp[64 * w + 16 * gate + cl];
                acc0[gate] = (f32x4){bv, bv, bv, bv};
                acc1[gate] = acc0[gate];
            }
            const unsigned short* Wb = P.Wt + ((size_t)(64 * w + cl)) * 256 + kq * 8;
            if (nmt == 2) {
                #pragma unroll
                for (int ks = 0; ks < 8; ++ks) {
                    const int kk = ks * 32;
                    const bf16x8 a0 = *(const bf16x8*)&S.uS[cl][kk + kq * 8];
                    const bf16x8 a1 = *(const bf16x8*)&S.uS[16 + cl][kk + kq * 8];
                    #pragma unroll
                    for (int gate = 0; gate < 4; ++gate) {
                        const bf16x8 bf = *(const bf16x8*)(Wb + (size_t)gate * 16 * 256 + kk);
                        acc0[gate] = __builtin_amdgcn_mfma_f32_16x16x32_bf16(a0, bf, acc0[gate], 0, 0, 0);
                        acc1[gate] = __builtin_amdgcn_mfma_f32_16x16x32_bf16(a1, bf, acc1[gate], 0, 0, 0);
                    }
                }
            } else {
                #pragma unroll
                for (int ks = 0; ks < 8; ++ks) {
                    const int kk = ks * 32;
                    const bf16x8 a0 = *(const bf16x8*)&S.uS[cl][kk + kq * 8];
                    #pragma unroll
                    for (int gate = 0; gate < 4; ++gate) {
                        const bf16x8 bf = *(const bf16x8*)(Wb + (size_t)gate * 16 * 256 + kk);
                        acc0[gate] = __builtin_amdgcn_mfma_f32_16x16x32_bf16(a0, bf, acc0[gate], 0, 0, 0);
                    }
                }
            }
            // ---- LSTM: lane-local i,f,g,o; ped m, unit r = 16w+cl (static acc idx) ----
            const int r = 16 * w + cl;
            #pragma unroll
            for (int reg = 0; reg < 4; ++reg) {
                const int m = 4 * kq + reg;
                if (m < ms) {
                    const int nl2 = (S.wL[base + m] >> 14) & 63;
                    const float cn2 = fmaf(sigf(acc0[1][reg]), S.cS[nl2][r],
                                           sigf(acc0[0][reg]) * tanh_f(acc0[2][reg]));
                    const float hv = sigf(acc0[3][reg]) * tanh_f(cn2);
                    S.hS[nl2][r] = hv;   // exclusive (node, r) per lane
                    S.cS[nl2][r] = cn2;
                }
            }
            if (nmt == 2) {
                #pragma unroll
                for (int reg = 0; reg < 4; ++reg) {
                    const int m = 16 + 4 * kq + reg;
                    if (m < ms) {
                        const int nl2 = (S.wL[base + m] >> 14) & 63;
                        const float cn2 = fmaf(sigf(acc1[1][reg]), S.cS[nl2][r],
                                               sigf(acc1[0][reg]) * tanh_f(acc1[2][reg]));
                        const float hv = sigf(acc1[3][reg]) * tanh_f(cn2);
                        S.hS[nl2][r] = hv;
                        S.cS[nl2][r] = cn2;
                    }
                }
            }
            __syncthreads();  // h_new visible for out-proj
            // ---- out projection (float4 LDS + transposed W_out). No trailing
            // barrier: next phase writes only uS, ordered by its own barrier. ----
            if (tid < ms * NOUT) {
                const int m = tid / NOUT, o = tid - m * NOUT;
                const int nl2 = (S.wL[base + m] >> 14) & 63;
                const float* hp = S.hS[nl2];
                const float* wp = P.W_outT + o * RNN;
                float a0 = P.b_out[o], a1 = 0.f, a2 = 0.f, a3 = 0.f;
                #pragma unroll 8
                for (int rr = 0; rr < RNN; rr += 4) {
                    const float4 h4 = *(const float4*)&hp[rr];
                    const float4 w4 = *(const float4*)&wp[rr];
                    a0 = fmaf(h4.x, w4.x, a0); a1 = fmaf(h4.y, w4.y, a1);
                    a2 = fmaf(h4.z, w4.z, a2); a3 = fmaf(h4.w, w4.w, a3);
                }
                P.outputs[((size_t)t * NN + n0 + nl2) * NOUT + o] = (a0 + a1) + (a2 + a3);
            }
        }

        // commit prefetched t+1 entries
        if (t + 1 < TT) {
            if (tid < CAP) S.eL[buf ^ 1][tid] = pf_e;
            if (tid == 0)  S.s_cnt[buf ^ 1] = (pf_c > CAP) ? CAP : pf_c;
        }
        __syncthreads();
    }

    // ---- epilogue: state writeback (coalesced) ----
    for (int i = tid; i < nown * RNN; i += NTHR) {
        int nl = i >> 7, r = i & 127;
        P.h_all[(size_t)n0 * RNN + i] = S.hS[nl][r];
        P.c_all[(size_t)n0 * RNN + i] = S.cS[nl][r];
    }
}

extern "C" void kernel_launch(void* const* d_in, const int* in_sizes, int n_in,
                              void* d_out, int out_size, void* d_ws, size_t ws_size,
                              hipStream_t stream) {
    Params P;
    P.input_data = (const float*)d_in[0];
    P.grids      = (const float*)d_in[1];
    P.h0         = (const float*)d_in[2];
    P.c0         = (const float*)d_in[3];
    const int* active_idx = (const int*)d_in[4];
    P.W_in  = (const float*)d_in[5];
    P.b_in  = (const float*)d_in[6];
    P.W_obs = (const float*)d_in[7];
    P.b_obs = (const float*)d_in[8];
    const float* W_ih = (const float*)d_in[9];
    const float* b_ih = (const float*)d_in[10];
    const float* W_hh = (const float*)d_in[11];
    const float* b_hh = (const float*)d_in[12];
    const float* W_out = (const float*)d_in[13];
    P.b_out = (const float*)d_in[14];

    // d_out: outputs[T*N*5] | h_fin[N*128] | c_fin[N*128]
    P.outputs = (float*)d_out;
    P.h_all   = P.outputs + (size_t)TT * NN * NOUT;
    P.c_all   = P.h_all + (size_t)NN * RNN;

    // d_ws: Wt (512x256 bf16) | biasp | W_outT (5x128) | cnt (TT*NBLK) | lists (TT*NBLK*CAP)
    char* ws = (char*)d_ws;
    unsigned short* Wt = (unsigned short*)ws;  ws += (size_t)512 * 256 * sizeof(unsigned short);
    float* biasp = (float*)ws;                 ws += 512 * sizeof(float);
    float* WoT   = (float*)ws;                 ws += (size_t)NOUT * RNN * sizeof(float);
    int* cnt     = (int*)ws;                   ws += (size_t)TT * NBLK * sizeof(int);
    int* lists   = (int*)ws;
    P.Wt = Wt; P.biasp = biasp; P.W_outT = WoT; P.cnt = cnt; P.lists = lists;

    hipMemsetAsync(P.outputs, 0, (size_t)TT * NN * NOUT * sizeof(float), stream);
    hipMemsetAsync(cnt, 0, (size_t)TT * NBLK * sizeof(int), stream);
    prep_kernel<<<512, 256, 0, stream>>>(W_ih, W_hh, b_ih, b_hh, W_out, Wt, biasp, WoT);
    bin_kernel<<<(TT * KK + 255) / 256, 256, 0, stream>>>(active_idx, cnt, lists);

    // ~73 KB dynamic LDS -> 2 blocks/CU (146.5 of 160 KB); attribute raise is host-side
    int smem = (int)sizeof(SmemT);
    hipFuncSetAttribute((const void*)olstm_kernel,
                        hipFuncAttributeMaxDynamicSharedMemorySize, smem);
    olstm_kernel<<<NBLK, NTHR, smem, stream>>>(P);
}

// Round 2
// 414.375 us; speedup vs baseline: 2.3547x; 2.3547x over previous
//
#include <hip/hip_runtime.h>

// OLSTM: T=20 frames, N=50000 nodes, K=10000 active peds/frame
// RNN=128, EMB=64, IN=2, OUT=5, G2=16
//
// Round 9: revert to NODEB=98 (round-7 structure, 636us) after round-8's
// occupancy-doubling regression proved costs are fixed per-block-frame.
// Attack the fixed costs instead:
//  - B-stationary GEMM: all 32 bf16x8 Wt fragments live in VGPRs for the
//    whole kernel (loaded once; 1 block/CU -> 256-VGPR budget, launch_bounds
//    (512,2)). No per-frame Wt L2 stream.
//  - winner_kernel precomputes winner lists (in-place compaction of bin
//    lists): no per-frame resolution/atomics, 2 fewer barriers.
//  - gathers for frame t+1 issued at top of frame t, committed at bottom
//    (double-buffered gX): HBM latency hidden under compute.
//  - small weights (W_obs/W_in/biases/biasp/W_outT) in LDS.
//  - 3 barriers/frame (+2 per extra 32-winner super-tile, rare).
#define TT    20
#define NN    50000
#define KK    10000
#define RNN   128
#define EMB   64
#define GG2   16
#define NOUT  5
#define NODEB 98
#define NBLK  ((NN + NODEB - 1) / NODEB)   // 511 blocks
#define CAP   64                           // peds per (frame, block); E[n]=19.6
#define NTHR  512                          // 8 waves

typedef __attribute__((ext_vector_type(8))) short bf16x8;
typedef __attribute__((ext_vector_type(4))) float f32x4;

__device__ __forceinline__ unsigned short f2b(float x) {  // fp32 -> bf16, RNE
    union { float f; unsigned u; } v; v.f = x;
    return (unsigned short)((v.u + 0x7FFF + ((v.u >> 16) & 1)) >> 16);
}
__device__ __forceinline__ unsigned pack2(float a, float b) {
    return (unsigned)f2b(a) | ((unsigned)f2b(b) << 16);
}
__device__ __forceinline__ float sigf(float x)   { return 1.f / (1.f + __expf(-x)); }
__device__ __forceinline__ float tanh_f(float x) { return 2.f / (1.f + __expf(-2.f * x)) - 1.f; }

struct Params {
    const float* input_data; const float* grids;
    const float* h0; const float* c0;
    const float* W_in;  const float* b_in;
    const float* W_obs; const float* b_obs;
    const float* b_out;
    float* outputs; float* h_all; float* c_all;
    const unsigned short* Wt; const float* biasp; const float* W_outT;
    int* cnt; int* lists;
};

struct SmemT {
    float hS[NODEB][132];          // owned h state, fp32 (pad 132: bank spread)
    float cS[NODEB][132];          // owned c state, fp32
    unsigned short uS[32][264];    // GEMM A: [ie(64) te(64) h(128)] bf16
    float gX[2][CAP][20];          // double-buffered per-winner grid(16)+x(2)
    float wObs[GG2][EMB];          // small weights, LDS-resident
    float wIn[2][EMB];
    float bIn[EMB];
    float bObs[EMB];
    float biasp[512];
    float wOutT[NOUT][RNN];
    float bOut[8];
    int wL[3][CAP];                // winner lists, 3-slot rotation (t%3)
    int wCnt[3];
};                                 // ~141.2 KB of 160 KB -> 1 block/CU

// bf16 transposed+permuted weights Wt[cp][k] (512x256) + fused bias:
// cp = 64*wq + 16*gate + cl  ->  orig col = 128*gate + 16*wq + cl.
// Consumer wave w takes cp in [64w, 64w+64): its 4 n-tiles = gates i,f,g,o for
// rnn unit r = 16w + cl  =>  lane-local LSTM. Also builds W_outT[o][r].
__global__ __launch_bounds__(256) void prep_kernel(
    const float* __restrict__ Wih, const float* __restrict__ Whh,
    const float* __restrict__ bih, const float* __restrict__ bhh,
    const float* __restrict__ Wout,
    unsigned short* __restrict__ Wt, float* __restrict__ biasp,
    float* __restrict__ WoutT)
{
    int cp = blockIdx.x;       // 0..511
    int k  = threadIdx.x;      // 0..255
    int wq = cp >> 6, rem = cp & 63, gate = rem >> 4, cl = rem & 15;
    int oc = 128 * gate + 16 * wq + cl;
    float v = (k < 128) ? Wih[k * 512 + oc] : Whh[(k - 128) * 512 + oc];
    Wt[cp * 256 + k] = f2b(v);
    if (k == 0) biasp[cp] = bih[oc] + bhh[oc];
    int e = cp * 256 + k;
    if (e < NOUT * RNN) WoutT[e] = Wout[(e & 127) * NOUT + (e >> 7)];
}

// Bin each (t,k) ped to its node-owner block. Entry = k | (node_local << 14).
__global__ __launch_bounds__(256) void bin_kernel(
    const int* __restrict__ idx, int* __restrict__ cnt, int* __restrict__ lists)
{
    int e = blockIdx.x * 256 + threadIdx.x;
    if (e >= TT * KK) return;
    int t = e / KK, k = e - t * KK;
    int nd = idx[e];
    int ow = nd / NODEB, nl = nd - ow * NODEB;
    int slot = atomicAdd(&cnt[t * NBLK + ow], 1);
    if (slot < CAP) lists[((size_t)(t * NBLK + ow)) * CAP + slot] = k | (nl << 14);
}

// Resolve winners per (t, block) ONCE, in-place: lists[g][0..w) <- winner
// entries (max-k per node), cnt[g] <- winner count. Single wave: in-order DS.
__global__ __launch_bounds__(64) void winner_kernel(
    int* __restrict__ cnt, int* __restrict__ lists)
{
    __shared__ int wslot[NODEB];
    const int g = blockIdx.x;          // t*NBLK + b
    const int lane = threadIdx.x;
    int c = cnt[g]; c = (c > CAP) ? CAP : c;
    wslot[lane] = -1;
    if (lane + 64 < NODEB) wslot[lane + 64] = -1;
    int ent = 0, mk = -1, mnl = 0;
    if (lane < c) {
        ent = lists[(size_t)g * CAP + lane];
        mnl = ent >> 14; mk = ent & 0x3FFF;
        atomicMax(&wslot[mnl], mk);
    }
    const bool win = (lane < c) && (wslot[mnl] == mk);
    const unsigned long long ball = __ballot(win);
    const int slot = __popcll(ball & ((1ull << lane) - 1ull));
    if (win) lists[(size_t)g * CAP + slot] = ent;   // reads all done (one vmem op)
    if (lane == 0) cnt[g] = __popcll(ball);
}

__global__ __launch_bounds__(NTHR, 2) void olstm_kernel(Params P) {
    extern __shared__ char smem_raw[];
    SmemT& S = *(SmemT*)smem_raw;
    const int tid = threadIdx.x;
    const int b   = blockIdx.x;
    const int n0  = b * NODEB;
    const int nown = (NN - n0 < NODEB) ? (NN - n0) : NODEB;
    const int w = tid >> 6, lane = tid & 63;
    const int cl = lane & 15, kq = lane >> 4;

    // ---- prologue: state + small weights -> LDS, winner lists t=0,1 ----
    for (int i = tid; i < nown * RNN; i += NTHR) {
        int nl = i >> 7, r = i & 127;
        S.hS[nl][r] = P.h0[(size_t)n0 * RNN + i];
        S.cS[nl][r] = P.c0[(size_t)n0 * RNN + i];
    }
    for (int i = tid; i < GG2 * EMB; i += NTHR) S.wObs[i >> 6][i & 63] = P.W_obs[i];
    if (tid < 2 * EMB) S.wIn[tid >> 6][tid & 63] = P.W_in[tid];
    if (tid < EMB) { S.bIn[tid] = P.b_in[tid]; S.bObs[tid] = P.b_obs[tid]; }
    if (tid < 512) S.biasp[tid] = P.biasp[tid];
    for (int i = tid; i < NOUT * RNN; i += NTHR) S.wOutT[i >> 7][i & 127] = P.W_outT[i];
    if (tid < NOUT) S.bOut[tid] = P.b_out[tid];
    if (tid < CAP) {
        S.wL[0][tid] = P.lists[(size_t)b * CAP + tid];
        S.wL[1][tid] = P.lists[((size_t)(NBLK + b)) * CAP + tid];
    }
    if (tid == 0) {
        S.wCnt[0] = P.cnt[b];
        S.wCnt[1] = P.cnt[NBLK + b];
        S.wCnt[2] = 0;
    }
    // ---- B-stationary: whole Wt tile for this lane -> 128 VGPRs, held all kernel ----
    bf16x8 Breg[4][8];
    {
        const unsigned short* Wb = P.Wt + ((size_t)(64 * w + cl)) * 256 + kq * 8;
        #pragma unroll
        for (int gate = 0; gate < 4; ++gate)
            #pragma unroll
            for (int ks = 0; ks < 8; ++ks)
                Breg[gate][ks] = *(const bf16x8*)(Wb + (size_t)gate * 16 * 256 + ks * 32);
    }
    __syncthreads();
    // ---- stage gX[0] (only frame whose gather latency is exposed) ----
    {
        const int wn0 = S.wCnt[0];
        if (tid < CAP) {
            if (tid < wn0) {
                int nl = S.wL[0][tid] >> 14;
                float2 xv = *(const float2*)(P.input_data + ((size_t)(n0 + nl)) * 2);
                S.gX[0][tid][16] = xv.x; S.gX[0][tid][17] = xv.y;
            }
        } else if (tid < 64 + 4 * CAP) {
            int gm0 = (tid - 64) >> 2;
            if (gm0 < wn0) {
                int kk2 = S.wL[0][gm0] & 0x3FFF;
                float4 gv = *(const float4*)(P.grids + (size_t)kk2 * GG2 + (tid & 3) * 4);
                *(float4*)&S.gX[0][gm0][(tid & 3) * 4] = gv;
            }
        }
    }
    __syncthreads();

    for (int t = 0; t < TT; ++t) {
        const int s_t  = t % 3;
        const int bufc = t & 1;
        const int wn   = S.wCnt[s_t];

        // ---- issue winner list t+2 (regs) + gathers for t+1 (regs) ----
        int pf_e = 0, pf_c = 0;
        if (t + 2 < TT) {
            if (tid < CAP) pf_e = P.lists[((size_t)((t + 2) * NBLK + b)) * CAP + tid];
            if (tid == 0)  pf_c = P.cnt[(t + 2) * NBLK + b];
        }
        float2 xv = {0.f, 0.f};
        float4 gv = {0.f, 0.f, 0.f, 0.f};
        int gm = 0, nwn = 0;
        if (t + 1 < TT) {
            const int sn = (t + 1) % 3;
            nwn = S.wCnt[sn];
            if (tid < CAP) {
                if (tid < nwn) {
                    int nl = S.wL[sn][tid] >> 14;
                    xv = *(const float2*)(P.input_data + ((size_t)(t + 1) * NN + n0 + nl) * 2);
                }
            } else if (tid < 64 + 4 * CAP) {
                gm = (tid - 64) >> 2;
                if (gm < nwn) {
                    int kk2 = S.wL[sn][gm] & 0x3FFF;
                    gv = *(const float4*)(P.grids + ((size_t)(t + 1) * KK + kk2) * GG2 + (tid & 3) * 4);
                }
            }
        }

        for (int base = 0; base < wn; base += 32) {
            const int ms = (wn - base < 32) ? (wn - base) : 32;
            const int nmt = (ms > 16) ? 2 : 1;         // skip m-tile 1 when ms<=16
            const int mrows = nmt << 4;
            // ---- fused uS build: h (float4 LDS -> bf16) + embeddings ----
            {
                const int m = tid >> 4, l = tid & 15;
                if (m < mrows) {
                    unsigned* du = (unsigned*)&S.uS[m][128 + l * 8];
                    unsigned* di = (unsigned*)&S.uS[m][l * 4];
                    unsigned* dt = (unsigned*)&S.uS[m][64 + l * 4];
                    if (m < ms) {
                        const int e = S.wL[s_t][base + m];
                        const int nl2 = e >> 14;
                        const float4 h0 = *(const float4*)&S.hS[nl2][l * 8];
                        const float4 h1 = *(const float4*)&S.hS[nl2][l * 8 + 4];
                        du[0] = pack2(h0.x, h0.y); du[1] = pack2(h0.z, h0.w);
                        du[2] = pack2(h1.x, h1.y); du[3] = pack2(h1.z, h1.w);
                        const float* gx = S.gX[bufc][base + m];
                        const float x0 = gx[16], x1 = gx[17];
                        const int e0 = l * 4;
                        float iv[4], tv[4];
                        #pragma unroll
                        for (int j = 0; j < 4; ++j) {
                            iv[j] = fmaxf(fmaf(x0, S.wIn[0][e0 + j],
                                          fmaf(x1, S.wIn[1][e0 + j], S.bIn[e0 + j])), 0.f);
                            tv[j] = S.bObs[e0 + j];
                        }
                        #pragma unroll
                        for (int g = 0; g < GG2; ++g) {
                            const float gg = gx[g];
                            #pragma unroll
                            for (int j = 0; j < 4; ++j)
                                tv[j] = fmaf(gg, S.wObs[g][e0 + j], tv[j]);
                        }
                        di[0] = pack2(iv[0], iv[1]); di[1] = pack2(iv[2], iv[3]);
                        dt[0] = pack2(fmaxf(tv[0], 0.f), fmaxf(tv[1], 0.f));
                        dt[1] = pack2(fmaxf(tv[2], 0.f), fmaxf(tv[3], 0.f));
                    } else {
                        du[0] = 0; du[1] = 0; du[2] = 0; du[3] = 0;
                        di[0] = 0; di[1] = 0; dt[0] = 0; dt[1] = 0;
                    }
                }
            }
            __syncthreads();

            // ---- gates GEMM (B from registers) + lane-local LSTM ----
            const int r = 16 * w + cl;
            f32x4 acc0[4];
            #pragma unroll
            for (int gate = 0; gate < 4; ++gate) {
                const float bv = S.biasp[64 * w + 16 * gate + cl];
                acc0[gate] = (f32x4){bv, bv, bv, bv};
            }
            if (nmt == 2) {
                f32x4 acc1[4];
                #pragma unroll
                for (int gate = 0; gate < 4; ++gate) acc1[gate] = acc0[gate];
                #pragma unroll
                for (int ks = 0; ks < 8; ++ks) {
                    const int kk = ks * 32;
                    const bf16x8 a0 = *(const bf16x8*)&S.uS[cl][kk + kq * 8];
                    const bf16x8 a1 = *(const bf16x8*)&S.uS[16 + cl][kk + kq * 8];
                    #pragma unroll
                    for (int gate = 0; gate < 4; ++gate) {
                        acc0[gate] = __builtin_amdgcn_mfma_f32_16x16x32_bf16(a0, Breg[gate][ks], acc0[gate], 0, 0, 0);
                        acc1[gate] = __builtin_amdgcn_mfma_f32_16x16x32_bf16(a1, Breg[gate][ks], acc1[gate], 0, 0, 0);
                    }
                }
                #pragma unroll
                for (int reg = 0; reg < 4; ++reg) {
                    const int m = 4 * kq + reg;
                    if (m < ms) {
                        const int nl2 = S.wL[s_t][base + m] >> 14;
                        const float cn2 = fmaf(sigf(acc0[1][reg]), S.cS[nl2][r],
                                               sigf(acc0[0][reg]) * tanh_f(acc0[2][reg]));
                        const float hv = sigf(acc0[3][reg]) * tanh_f(cn2);
                        S.hS[nl2][r] = hv;   // exclusive (node, r) per lane
                        S.cS[nl2][r] = cn2;
                    }
                }
                #pragma unroll
                for (int reg = 0; reg < 4; ++reg) {
                    const int m = 16 + 4 * kq + reg;
                    if (m < ms) {
                        const int nl2 = S.wL[s_t][base + m] >> 14;
                        const float cn2 = fmaf(sigf(acc1[1][reg]), S.cS[nl2][r],
                                               sigf(acc1[0][reg]) * tanh_f(acc1[2][reg]));
                        const float hv = sigf(acc1[3][reg]) * tanh_f(cn2);
                        S.hS[nl2][r] = hv;
                        S.cS[nl2][r] = cn2;
                    }
                }
            } else {
                #pragma unroll
                for (int ks = 0; ks < 8; ++ks) {
                    const int kk = ks * 32;
                    const bf16x8 a0 = *(const bf16x8*)&S.uS[cl][kk + kq * 8];
                    #pragma unroll
                    for (int gate = 0; gate < 4; ++gate)
                        acc0[gate] = __builtin_amdgcn_mfma_f32_16x16x32_bf16(a0, Breg[gate][ks], acc0[gate], 0, 0, 0);
                }
                #pragma unroll
                for (int reg = 0; reg < 4; ++reg) {
                    const int m = 4 * kq + reg;
                    if (m < ms) {
                        const int nl2 = S.wL[s_t][base + m] >> 14;
                        const float cn2 = fmaf(sigf(acc0[1][reg]), S.cS[nl2][r],
                                               sigf(acc0[0][reg]) * tanh_f(acc0[2][reg]));
                        const float hv = sigf(acc0[3][reg]) * tanh_f(cn2);
                        S.hS[nl2][r] = hv;
                        S.cS[nl2][r] = cn2;
                    }
                }
            }
            __syncthreads();  // h_new visible for out-proj
            // ---- out projection (float4 LDS, W_outT in LDS) ----
            if (tid < ms * NOUT) {
                const int m = tid / NOUT, o = tid - m * NOUT;
                const int nl2 = S.wL[s_t][base + m] >> 14;
                const float* hp = S.hS[nl2];
                const float* wp = S.wOutT[o];
                float a0 = S.bOut[o], a1 = 0.f, a2 = 0.f, a3 = 0.f;
                #pragma unroll 8
                for (int rr = 0; rr < RNN; rr += 4) {
                    const float4 h4 = *(const float4*)&hp[rr];
                    const float4 w4 = *(const float4*)&wp[rr];
                    a0 = fmaf(h4.x, w4.x, a0); a1 = fmaf(h4.y, w4.y, a1);
                    a2 = fmaf(h4.z, w4.z, a2); a3 = fmaf(h4.w, w4.w, a3);
                }
                P.outputs[((size_t)t * NN + n0 + nl2) * NOUT + o] = (a0 + a1) + (a2 + a3);
            }
        }

        // ---- commit prefetched gX[t+1] and wL[t+2] (loads issued ~whole frame ago) ----
        if (t + 1 < TT) {
            if (tid < CAP) {
                if (tid < nwn) { S.gX[bufc ^ 1][tid][16] = xv.x; S.gX[bufc ^ 1][tid][17] = xv.y; }
            } else if (tid < 64 + 4 * CAP) {
                if (gm < nwn) *(float4*)&S.gX[bufc ^ 1][gm][(tid & 3) * 4] = gv;
            }
        }
        if (t + 2 < TT) {
            if (tid < CAP) S.wL[(t + 2) % 3][tid] = pf_e;
            if (tid == 0)  S.wCnt[(t + 2) % 3] = (pf_c > CAP) ? CAP : pf_c;
        }
        __syncthreads();
    }

    // ---- epilogue: state writeback (coalesced) ----
    for (int i = tid; i < nown * RNN; i += NTHR) {
        int nl = i >> 7, r = i & 127;
        P.h_all[(size_t)n0 * RNN + i] = S.hS[nl][r];
        P.c_all[(size_t)n0 * RNN + i] = S.cS[nl][r];
    }
}

extern "C" void kernel_launch(void* const* d_in, const int* in_sizes, int n_in,
                              void* d_out, int out_size, void* d_ws, size_t ws_size,
                              hipStream_t stream) {
    Params P;
    P.input_data = (const float*)d_in[0];
    P.grids      = (const float*)d_in[1];
    P.h0         = (const float*)d_in[2];
    P.c0         = (const float*)d_in[3];
    const int* active_idx = (const int*)d_in[4];
    P.W_in  = (const float*)d_in[5];
    P.b_in  = (const float*)d_in[6];
    P.W_obs = (const float*)d_in[7];
    P.b_obs = (const float*)d_in[8];
    const float* W_ih = (const float*)d_in[9];
    const float* b_ih = (const float*)d_in[10];
    const float* W_hh = (const float*)d_in[11];
    const float* b_hh = (const float*)d_in[12];
    const float* W_out = (const float*)d_in[13];
    P.b_out = (const float*)d_in[14];

    // d_out: outputs[T*N*5] | h_fin[N*128] | c_fin[N*128]
    P.outputs = (float*)d_out;
    P.h_all   = P.outputs + (size_t)TT * NN * NOUT;
    P.c_all   = P.h_all + (size_t)NN * RNN;

    // d_ws: Wt (512x256 bf16) | biasp | W_outT (5x128) | cnt (TT*NBLK) | lists (TT*NBLK*CAP)
    char* ws = (char*)d_ws;
    unsigned short* Wt = (unsigned short*)ws;  ws += (size_t)512 * 256 * sizeof(unsigned short);
    float* biasp = (float*)ws;                 ws += 512 * sizeof(float);
    float* WoT   = (float*)ws;                 ws += (size_t)NOUT * RNN * sizeof(float);
    int* cnt     = (int*)ws;                   ws += (size_t)TT * NBLK * sizeof(int);
    int* lists   = (int*)ws;
    P.Wt = Wt; P.biasp = biasp; P.W_outT = WoT; P.cnt = cnt; P.lists = lists;

    hipMemsetAsync(P.outputs, 0, (size_t)TT * NN * NOUT * sizeof(float), stream);
    hipMemsetAsync(cnt, 0, (size_t)TT * NBLK * sizeof(int), stream);
    prep_kernel<<<512, 256, 0, stream>>>(W_ih, W_hh, b_ih, b_hh, W_out, Wt, biasp, WoT);
    bin_kernel<<<(TT * KK + 255) / 256, 256, 0, stream>>>(active_idx, cnt, lists);
    winner_kernel<<<TT * NBLK, 64, 0, stream>>>(cnt, lists);

    // ~141 KB dynamic LDS (gfx950: 160 KB/CU) -> 1 block/CU, 8 waves
    int smem = (int)sizeof(SmemT);
    hipFuncSetAttribute((const void*)olstm_kernel,
                        hipFuncAttributeMaxDynamicSharedMemorySize, smem);
    olstm_kernel<<<NBLK, NTHR, smem, stream>>>(P);
}